// Round 15
// baseline (38.426 us; speedup 1.0000x reference)
//
#include <hip/hip_runtime.h>
#include <hip/hip_bf16.h>

// B=2048, NF=64, FD=32, S=32, D=32, OD=32
typedef __attribute__((ext_vector_type(4)))  _Float16 h4;
typedef __attribute__((ext_vector_type(8)))  _Float16 h8;
typedef __attribute__((ext_vector_type(4)))  float f32x4;
typedef __attribute__((ext_vector_type(16))) float f32x16;
typedef __attribute__((ext_vector_type(4)))  unsigned int u32x4;

__device__ __forceinline__ int sdecode(int sp) { return ((sp & 7) << 2) | (sp >> 3); }

// ---------------- prep: conv units (bid<512, one 64-thr unit per wave)
//                  + xconv (bid>=512): xh[s][b][64] f16, all streams coalesced ----
__global__ __launch_bounds__(256) void prep_kernel(
    const float* __restrict__ Rg, const float* __restrict__ Og,
    const float* __restrict__ x,
    _Float16* __restrict__ Rb, char* __restrict__ Opp, char* __restrict__ xh)
{
    __shared__ float tiles[4][32][34];
    const int bid = blockIdx.x;
    const int t = threadIdx.x, wid = t >> 6, l = t & 63;

    if (bid < 512) {
        const int obid = bid*4 + wid;
        const int s = sdecode(obid & 31), q = (obid >> 5) & 31, which = obid >> 10;
        float (*tile)[34] = tiles[wid];
        const int tl = l & 31, th = l >> 5;

        if (which == 0) {
            #pragma unroll
            for (int j = 0; j < 16; ++j) {          // tile[n][a] = R[s][q][a][n]
                int ar = 2*j + th;
                tile[tl][ar] = Rg[(((size_t)s*32 + q)*32 + ar)*32 + tl];
            }
        } else {
            #pragma unroll
            for (int j = 0; j < 16; ++j) {          // tile[o][n] = O[s][q][n][o]
                int nr = 2*j + th;
                tile[tl][nr] = Og[(((size_t)s*32 + q)*32 + nr)*32 + tl];
            }
        }
        __syncthreads();
        if (which == 0) {
            _Float16* dst = Rb + ((size_t)s*32 + q)*1024;   // Rb[s][g=q][n][a]
            #pragma unroll
            for (int it = 0; it < 4; ++it) {
                int nr = it*8 + (l >> 3), a0 = (l & 7)*4;
                h4 w;
                #pragma unroll
                for (int k = 0; k < 4; ++k) w[k] = (_Float16)tile[nr][a0 + k];
                *(h4*)(dst + nr*32 + a0) = w;
            }
        } else {
            char* dst = Opp + (size_t)s*65536 + q*2048;     // Opp[s][c8][o][kk]
            int o = l & 31, cq = l >> 5;
            #pragma unroll
            for (int it = 0; it < 2; ++it) {
                int c = it*2 + cq;
                h8 w;
                #pragma unroll
                for (int k = 0; k < 8; ++k) w[k] = (_Float16)tile[o][c*8 + k];
                *(h8*)(dst + c*512 + o*16) = w;
            }
        }
    } else {
        // xconv: 32 b-rows per block, reads 2KB/wave-instr, writes 16B/thread
        const int xbid = bid - 512;                 // 0..63
        const int b0x = xbid * 32;
        const float* xb = x + (size_t)b0x * 2048;
        #pragma unroll 4
        for (int c = 0; c < 32; ++c) {
            int g = c*256 + t;                      // 8-float unit
            float4 v0 = *(const float4*)(xb + (size_t)g*8);
            float4 v1 = *(const float4*)(xb + (size_t)g*8 + 4);
            h8 w;
            w[0] = (_Float16)v0.x; w[1] = (_Float16)v0.y;
            w[2] = (_Float16)v0.z; w[3] = (_Float16)v0.w;
            w[4] = (_Float16)v1.x; w[5] = (_Float16)v1.y;
            w[6] = (_Float16)v1.z; w[7] = (_Float16)v1.w;
            int row = g >> 8;                       // 0..31
            int s2 = (g & 255) >> 3;                // s
            int cf = (g & 7) * 8;                   // col within 64
            *(h8*)(xh + ((size_t)s2*2048 + b0x + row)*128 + cf*2) = w;
        }
    }
}

// ---------------- tmake: Tp[s][ks=f*2+gt][o][kk] (unchanged) ----
__global__ __launch_bounds__(256, 2) void tmake_kernel(
    const float* __restrict__ Lg, const _Float16* __restrict__ Rb,
    const char* __restrict__ Opp, char* __restrict__ Tp)
{
    __shared__ __align__(16) char Wl[65536];
    const int bid = blockIdx.x;
    const int s = sdecode(bid & 31), f = bid >> 5;
    const int t = threadIdx.x, wid = t >> 6, l = t & 63;
    const int llo = l & 15, lhi = l >> 4;

    const float* Lsf = Lg + ((size_t)s*32 + f)*1024;
    h8 bfr[2];
    #pragma unroll
    for (int mt = 0; mt < 2; ++mt)
        #pragma unroll
        for (int j = 0; j < 8; ++j)
            bfr[mt][j] = (_Float16)Lsf[(8*lhi + j)*32 + mt*16 + llo];

    const _Float16* Rbs = Rb + (size_t)s*32768;

    #pragma unroll 4
    for (int nt = 0; nt < 16; ++nt) {
        int gnb = (wid*16 + nt)*16;
        h8 af = *(const h8*)(Rbs + (gnb + llo)*32 + 8*lhi);
        int g = gnb >> 5;
        int nbase = (gnb & 31) + 4*lhi;
        #pragma unroll
        for (int mt = 0; mt < 2; ++mt) {
            f32x4 d = __builtin_amdgcn_mfma_f32_16x16x32_f16(af, bfr[mt], (f32x4)(0.f), 0, 0, 0);
            int m = mt*16 + llo;
            h4 w;
            #pragma unroll
            for (int r = 0; r < 4; ++r) w[r] = (_Float16)d[r];
            int byte = (g*2048 + m*64 + nbase*2) ^ ((((g & 7) ^ (m & 7))) << 4);
            *(h4*)(Wl + byte) = w;
        }
    }
    __syncthreads();

    const int ot = wid & 1, kq = wid >> 1;
    const int orow = ot*16 + llo;
    const char* Opps = Opp + (size_t)s*65536;
    f32x4 acc0 = (f32x4)(0.f), acc1 = (f32x4)(0.f);
    #pragma unroll 4
    for (int ksl = 0; ksl < 16; ++ksl) {
        int ks = kq*16 + ksl;
        h8 bf = *(const h8*)(Opps + (ks*4 + lhi)*512 + orow*16);
        {
            int grow = llo;
            int byte = (grow*2048 + ks*64 + lhi*16) ^ ((((grow & 7) ^ (ks & 7))) << 4);
            h8 af = *(const h8*)(Wl + byte);
            acc0 = __builtin_amdgcn_mfma_f32_16x16x32_f16(af, bf, acc0, 0, 0, 0);
        }
        {
            int grow = 16 + llo;
            int byte = (grow*2048 + ks*64 + lhi*16) ^ ((((grow & 7) ^ (ks & 7))) << 4);
            h8 af = *(const h8*)(Wl + byte);
            acc1 = __builtin_amdgcn_mfma_f32_16x16x32_f16(af, bf, acc1, 0, 0, 0);
        }
    }
    __syncthreads();
    if (kq == 1) {
        *(f32x4*)(Wl + ((ot*2 + 0)*64 + l)*16) = acc0;
        *(f32x4*)(Wl + ((ot*2 + 1)*64 + l)*16) = acc1;
    }
    __syncthreads();
    if (kq == 0) {
        acc0 += *(const f32x4*)(Wl + ((ot*2 + 0)*64 + l)*16);
        acc1 += *(const f32x4*)(Wl + ((ot*2 + 1)*64 + l)*16);
        char* Tps = Tp + (size_t)s*65536;
        h4 w0, w1;
        #pragma unroll
        for (int r = 0; r < 4; ++r) { w0[r] = (_Float16)acc0[r]; w1[r] = (_Float16)acc1[r]; }
        *(h4*)(Tps + (f*2 + 0)*1024 + orow*32 + lhi*8) = w0;
        *(h4*)(Tps + (f*2 + 1)*1024 + orow*32 + lhi*8) = w1;
    }
}

// ---------------- main v8: BT=256, 512 thr, xh input, outT output (all dense)
// grid 256 = (sp = bid&31, btile = bid>>5). One barrier. No bias (in outtrans).
__global__ __launch_bounds__(512, 2) void main_kernel(
    const char* __restrict__ xh, const char* __restrict__ Tp,
    char* __restrict__ outT)
{
    __shared__ __align__(16) char Tl[65536];

    const int bid = blockIdx.x;
    const int s = sdecode(bid & 31);
    const int b0 = (bid >> 5) * 256;
    const int t = threadIdx.x, wid = t >> 6, l = t & 63;
    const int lo5 = l & 31, hi = l >> 5;

    const char* Tps = Tp + (size_t)s*65536;
    const int b = b0 + wid*32 + lo5;
    const char* xrow = xh + ((size_t)s*2048 + b)*128;

    // ---- stage T (8 x 16B/thread = 64KB) + per-lane xh loads (f16 direct) ----
    u32x4 tv[8];
    #pragma unroll
    for (int i = 0; i < 8; ++i)
        tv[i] = *(const u32x4*)(Tps + (i*512 + t)*16);

    h8 xlh8[4];
    #pragma unroll
    for (int i = 0; i < 4; ++i) xlh8[i] = *(const h8*)(xrow + i*16);
    h8 xr_a = *(const h8*)(xrow + 64 + hi*16);
    h8 xr_b = *(const h8*)(xrow + 96 + hi*16);

    #pragma unroll
    for (int i = 0; i < 8; ++i)
        *(u32x4*)(Tl + (i*512 + t)*16) = tv[i];
    __syncthreads();

    // ---- K loop: 64 steps, 1 ds_read_b128 + 1 MFMA, acc ILP=2 ----
    f32x16 acc_e = (f32x16)(0.f), acc_o = (f32x16)(0.f);
    #pragma unroll
    for (int ksl = 0; ksl < 64; ++ksl) {
        h8 bf = *(const h8*)(Tl + ksl*1024 + lo5*32 + hi*16);
        _Float16 xs = xlh8[ksl >> 4][(ksl >> 1) & 7];
        if (ksl & 1) {
            h8 z = xr_b * xs;
            acc_o = __builtin_amdgcn_mfma_f32_32x32x16_f16(z, bf, acc_o, 0, 0, 0);
        } else {
            h8 z = xr_a * xs;
            acc_e = __builtin_amdgcn_mfma_f32_32x32x16_f16(z, bf, acc_e, 0, 0, 0);
        }
    }
    f32x16 acc = acc_e + acc_o;

    // ---- epilogue: stash per-wave tiles in Tl (dead), dense 32KB outT write ----
    __syncthreads();
    #pragma unroll
    for (int r = 0; r < 16; ++r) {
        int row = (r & 3) + 8*(r >> 2) + 4*hi;          // local 0..31
        *(float*)(Tl + wid*4096 + row*128 + lo5*4) = acc[r];
    }
    __syncthreads();

    #pragma unroll
    for (int i = 0; i < 4; ++i) {
        int u = i*512 + t;                 // row = u>>3 (0..255), colq = u&7
        int row = u >> 3, colq = u & 7;
        f32x4 v = *(const f32x4*)(Tl + u*16);
        *(f32x4*)(outT + ((size_t)s*2048 + b0 + row)*128 + colq*16) = v;
    }
}

// ---------------- outtrans: out[b][s*32+o] = outT[s][b][o] + bias[s][o]
// grid 128 (16 b-rows each); XOR-swizzled 64KB LDS; all bursts >= 2KB ----
__global__ __launch_bounds__(256) void outtrans_kernel(
    const char* __restrict__ outT, const float* __restrict__ bias,
    float* __restrict__ out)
{
    __shared__ __align__(16) char lds[65536];   // logical [16][256 units of 16B]
    const int bid = blockIdx.x;
    const int b0 = bid * 16;
    const int t = threadIdx.x;

    #pragma unroll
    for (int sp2 = 0; sp2 < 16; ++sp2) {
        int s = sp2*2 + (t >> 7);
        int u = t & 127, row = u >> 3, colq = u & 7;
        f32x4 v = *(const f32x4*)(outT + ((size_t)s*2048 + b0 + row)*128 + colq*16);
        f32x4 bv = *(const f32x4*)(bias + s*32 + colq*4);
        v = v + bv;
        int cu = s*8 + (colq ^ (row & 7));          // XOR swizzle low 3 bits
        *(f32x4*)(lds + row*4096 + cu*16) = v;
    }
    __syncthreads();

    #pragma unroll
    for (int r2 = 0; r2 < 16; ++r2) {
        f32x4 v = *(const f32x4*)(lds + r2*4096 + (t ^ (r2 & 7))*16);
        *(f32x4*)(out + (size_t)(b0 + r2)*1024 + t*4) = v;
    }
}

extern "C" void kernel_launch(void* const* d_in, const int* in_sizes, int n_in,
                              void* d_out, int out_size, void* d_ws, size_t ws_size,
                              hipStream_t stream) {
    const float* x    = (const float*)d_in[0];
    const float* L    = (const float*)d_in[1];
    const float* R    = (const float*)d_in[2];
    const float* O    = (const float*)d_in[3];
    const float* bias = (const float*)d_in[4];
    float* out = (float*)d_out;

    _Float16* Rb   = (_Float16*)d_ws;                  // 2 MB
    char*     Opp  = (char*)d_ws + 2097152;            // 2 MB
    char*     Tp   = (char*)d_ws + 4194304;            // 2 MB
    char*     outT = (char*)d_ws + 6291456;            // 8 MB  (f32 [s][b][32])
    char*     xh   = (char*)d_ws + 14680064;           // 8 MB  (f16 [s][b][64])

    prep_kernel<<<dim3(576), 256, 0, stream>>>(R, O, x, Rb, Opp, xh);
    tmake_kernel<<<dim3(1024), 256, 0, stream>>>(L, Rb, Opp, Tp);
    main_kernel<<<dim3(256), 512, 0, stream>>>(xh, Tp, outT);
    outtrans_kernel<<<dim3(128), 256, 0, stream>>>(outT, bias, out);
}

// Round 16
// 32.440 us; speedup vs baseline: 1.1845x; 1.1845x over previous
//
#include <hip/hip_runtime.h>
#include <hip/hip_bf16.h>

// B=2048, NF=64, FD=32, S=32, D=32, OD=32
typedef __attribute__((ext_vector_type(4)))  _Float16 h4;
typedef __attribute__((ext_vector_type(8)))  _Float16 h8;
typedef __attribute__((ext_vector_type(4)))  float f32x4;
typedef __attribute__((ext_vector_type(16))) float f32x16;
typedef __attribute__((ext_vector_type(4)))  unsigned int u32x4;

#define XH_STRIDE 262400   // 2048*128 + 256 (channel-rotating s-stride)

__device__ __forceinline__ int sdecode(int sp) { return ((sp & 7) << 2) | (sp >> 3); }

// ---------------- conv: Rb[s][g][n][a] f16 ; Opp[s][c8][o][kk] ----
__global__ __launch_bounds__(64) void conv_kernel(
    const float* __restrict__ Rg, const float* __restrict__ Og,
    _Float16* __restrict__ Rb, char* __restrict__ Opp)
{
    __shared__ float tile[32][33];
    const int bid = blockIdx.x;
    const int s = sdecode(bid & 31), q = (bid >> 5) & 31, which = bid >> 10;
    const int t = threadIdx.x, tl = t & 31, th = t >> 5;

    if (which == 0) {
        #pragma unroll
        for (int j = 0; j < 16; ++j) {
            int ar = 2*j + th;
            tile[tl][ar] = Rg[(((size_t)s*32 + q)*32 + ar)*32 + tl];
        }
        __syncthreads();
        _Float16* dst = Rb + ((size_t)s*32 + q)*1024;
        #pragma unroll
        for (int it = 0; it < 4; ++it) {
            int nr = it*8 + (t >> 3), a0 = (t & 7)*4;
            h4 w;
            #pragma unroll
            for (int k = 0; k < 4; ++k) w[k] = (_Float16)tile[nr][a0 + k];
            *(h4*)(dst + nr*32 + a0) = w;
        }
    } else {
        #pragma unroll
        for (int j = 0; j < 16; ++j) {
            int nr = 2*j + th;
            tile[tl][nr] = Og[(((size_t)s*32 + q)*32 + nr)*32 + tl];
        }
        __syncthreads();
        char* dst = Opp + (size_t)s*65536 + q*2048;
        int o = t & 31, cq = t >> 5;
        #pragma unroll
        for (int it = 0; it < 2; ++it) {
            int c = it*2 + cq;
            h8 w;
            #pragma unroll
            for (int k = 0; k < 8; ++k) w[k] = (_Float16)tile[o][c*8 + k];
            *(h8*)(dst + c*512 + o*16) = w;
        }
    }
}

// ---------------- tmake (+ fused xconv): Tp[s][ks][o][kk]; xh[s][b][64] f16 ----
__global__ __launch_bounds__(256, 2) void tmake_kernel(
    const float* __restrict__ Lg, const _Float16* __restrict__ Rb,
    const char* __restrict__ Opp, char* __restrict__ Tp,
    const float* __restrict__ x, char* __restrict__ xh)
{
    __shared__ __align__(16) char Wl[65536];
    const int bid = blockIdx.x;
    const int s = sdecode(bid & 31), f = bid >> 5;
    const int t = threadIdx.x, wid = t >> 6, l = t & 63;
    const int llo = l & 15, lhi = l >> 4;

    // ---- fused xconv: 2 x 8-float units per thread, dense read, f16 write ----
    {
        const int u0 = (bid*256 + t)*2;
        #pragma unroll
        for (int k = 0; k < 2; ++k) {
            int u = u0 + k;
            int b = u >> 8, pos = u & 255, s2 = pos >> 3, c = pos & 7;
            float4 v0 = *(const float4*)(x + (size_t)u*8);
            float4 v1 = *(const float4*)(x + (size_t)u*8 + 4);
            h8 w;
            w[0] = (_Float16)v0.x; w[1] = (_Float16)v0.y;
            w[2] = (_Float16)v0.z; w[3] = (_Float16)v0.w;
            w[4] = (_Float16)v1.x; w[5] = (_Float16)v1.y;
            w[6] = (_Float16)v1.z; w[7] = (_Float16)v1.w;
            *(h8*)(xh + (size_t)s2*XH_STRIDE + b*128 + c*16) = w;
        }
    }

    const float* Lsf = Lg + ((size_t)s*32 + f)*1024;
    h8 bfr[2];
    #pragma unroll
    for (int mt = 0; mt < 2; ++mt)
        #pragma unroll
        for (int j = 0; j < 8; ++j)
            bfr[mt][j] = (_Float16)Lsf[(8*lhi + j)*32 + mt*16 + llo];

    const _Float16* Rbs = Rb + (size_t)s*32768;

    #pragma unroll 4
    for (int nt = 0; nt < 16; ++nt) {
        int gnb = (wid*16 + nt)*16;
        h8 af = *(const h8*)(Rbs + (gnb + llo)*32 + 8*lhi);
        int g = gnb >> 5;
        int nbase = (gnb & 31) + 4*lhi;
        #pragma unroll
        for (int mt = 0; mt < 2; ++mt) {
            f32x4 d = __builtin_amdgcn_mfma_f32_16x16x32_f16(af, bfr[mt], (f32x4)(0.f), 0, 0, 0);
            int m = mt*16 + llo;
            h4 w;
            #pragma unroll
            for (int r = 0; r < 4; ++r) w[r] = (_Float16)d[r];
            int byte = (g*2048 + m*64 + nbase*2) ^ ((((g & 7) ^ (m & 7))) << 4);
            *(h4*)(Wl + byte) = w;
        }
    }
    __syncthreads();

    const int ot = wid & 1, kq = wid >> 1;
    const int orow = ot*16 + llo;
    const char* Opps = Opp + (size_t)s*65536;
    f32x4 acc0 = (f32x4)(0.f), acc1 = (f32x4)(0.f);
    #pragma unroll 4
    for (int ksl = 0; ksl < 16; ++ksl) {
        int ks = kq*16 + ksl;
        h8 bf = *(const h8*)(Opps + (ks*4 + lhi)*512 + orow*16);
        {
            int grow = llo;
            int byte = (grow*2048 + ks*64 + lhi*16) ^ ((((grow & 7) ^ (ks & 7))) << 4);
            h8 af = *(const h8*)(Wl + byte);
            acc0 = __builtin_amdgcn_mfma_f32_16x16x32_f16(af, bf, acc0, 0, 0, 0);
        }
        {
            int grow = 16 + llo;
            int byte = (grow*2048 + ks*64 + lhi*16) ^ ((((grow & 7) ^ (ks & 7))) << 4);
            h8 af = *(const h8*)(Wl + byte);
            acc1 = __builtin_amdgcn_mfma_f32_16x16x32_f16(af, bf, acc1, 0, 0, 0);
        }
    }
    __syncthreads();
    if (kq == 1) {
        *(f32x4*)(Wl + ((ot*2 + 0)*64 + l)*16) = acc0;
        *(f32x4*)(Wl + ((ot*2 + 1)*64 + l)*16) = acc1;
    }
    __syncthreads();
    if (kq == 0) {
        acc0 += *(const f32x4*)(Wl + ((ot*2 + 0)*64 + l)*16);
        acc1 += *(const f32x4*)(Wl + ((ot*2 + 1)*64 + l)*16);
        char* Tps = Tp + (size_t)s*65536;
        h4 w0, w1;
        #pragma unroll
        for (int r = 0; r < 4; ++r) { w0[r] = (_Float16)acc0[r]; w1[r] = (_Float16)acc1[r]; }
        *(h4*)(Tps + (f*2 + 0)*1024 + orow*32 + lhi*8) = w0;
        *(h4*)(Tps + (f*2 + 1)*1024 + orow*32 + lhi*8) = w1;
    }
}

// ---------------- main v9: v3 schedule, x from xh (dense 128B rows, f16)
// grid 512 (sp = bid&31, btile = bid>>5, BT=128), 256 thr, one barrier.
__global__ __launch_bounds__(256, 2) void main_kernel(
    const char* __restrict__ xh, const char* __restrict__ Tp,
    const float* __restrict__ bias, float* __restrict__ out)
{
    __shared__ __align__(16) char Tl[65536];

    const int bid = blockIdx.x;
    const int s = sdecode(bid & 31);
    const int b0 = (bid >> 5) * 128;
    const int t = threadIdx.x, wid = t >> 6, l = t & 63;
    const int lo5 = l & 31, hi = l >> 5;

    const char* Tps = Tp + (size_t)s*65536;
    const char* xrow = xh + (size_t)s*XH_STRIDE + (b0 + wid*32 + lo5)*128;

    // ---- stage T (16 x 16B/thread) + per-lane xh loads (f16 direct) ----
    u32x4 tv[16];
    #pragma unroll
    for (int i = 0; i < 16; ++i)
        tv[i] = *(const u32x4*)(Tps + (i*256 + t)*16);

    h8 xlh8[4];
    #pragma unroll
    for (int i = 0; i < 4; ++i) xlh8[i] = *(const h8*)(xrow + i*16);
    h8 xr_a = *(const h8*)(xrow + 64 + hi*16);
    h8 xr_b = *(const h8*)(xrow + 96 + hi*16);

    #pragma unroll
    for (int i = 0; i < 16; ++i)
        *(u32x4*)(Tl + (i*256 + t)*16) = tv[i];
    __syncthreads();

    // ---- K loop: 64 steps, 1 ds_read_b128 + 1 MFMA, acc ILP=2 ----
    f32x16 acc_e = (f32x16)(0.f), acc_o = (f32x16)(0.f);
    #pragma unroll
    for (int ksl = 0; ksl < 64; ++ksl) {
        h8 bf = *(const h8*)(Tl + ksl*1024 + lo5*32 + hi*16);
        _Float16 xs = xlh8[ksl >> 4][(ksl >> 1) & 7];
        if (ksl & 1) {
            h8 z = xr_b * xs;
            acc_o = __builtin_amdgcn_mfma_f32_32x32x16_f16(z, bf, acc_o, 0, 0, 0);
        } else {
            h8 z = xr_a * xs;
            acc_e = __builtin_amdgcn_mfma_f32_32x32x16_f16(z, bf, acc_e, 0, 0, 0);
        }
    }
    f32x16 acc = acc_e + acc_o;

    // ---- epilogue: stash in Tl (dead), vectorized full-line f32x4 stores ----
    __syncthreads();
    #pragma unroll
    for (int r = 0; r < 16; ++r) {
        int row = (r & 3) + 8*(r >> 2) + 4*hi;          // 32x32 C/D row map
        *(float*)(Tl + wid*4096 + row*128 + lo5*4) = acc[r];
    }
    __syncthreads();

    const float* bias_s = bias + s*32;
    #pragma unroll
    for (int i = 0; i < 4; ++i) {
        int u = i*256 + t;
        int row = u >> 3, colq = u & 7;
        f32x4 v = *(const f32x4*)(Tl + u*16);
        f32x4 bv = *(const f32x4*)(bias_s + colq*4);
        *(f32x4*)(out + (size_t)(b0 + row)*1024 + s*32 + colq*4) = v + bv;
    }
}

extern "C" void kernel_launch(void* const* d_in, const int* in_sizes, int n_in,
                              void* d_out, int out_size, void* d_ws, size_t ws_size,
                              hipStream_t stream) {
    const float* x    = (const float*)d_in[0];
    const float* L    = (const float*)d_in[1];
    const float* R    = (const float*)d_in[2];
    const float* O    = (const float*)d_in[3];
    const float* bias = (const float*)d_in[4];
    float* out = (float*)d_out;

    _Float16* Rb  = (_Float16*)d_ws;                 // 2 MB
    char*     Opp = (char*)d_ws + 2097152;           // 2 MB
    char*     Tp  = (char*)d_ws + 4194304;           // 2 MB
    char*     xh  = (char*)d_ws + 6291456;           // 8.4 MB (f16 [s][b][64], padded)

    conv_kernel<<<dim3(2048), 64, 0, stream>>>(R, O, Rb, Opp);
    tmake_kernel<<<dim3(1024), 256, 0, stream>>>(L, Rb, Opp, Tp, x, xh);
    main_kernel<<<dim3(512), 256, 0, stream>>>(xh, Tp, bias, out);
}